// Round 4
// baseline (2834.450 us; speedup 1.0000x reference)
//
#include <hip/hip_runtime.h>

// 2-layer LSTM (H=128) + FC, batch-parallel persistent kernel, round 4.
//
// History: r1/r3 designs needed 192 weight VGPRs but the allocator never
// grants >128 here (observed grants: 128 @ min-2-waves hint, 64 @ small-LDS,
// 128 @ 92KB-LDS) -> partial spill to scratch (87 MB WRITE churn in r3).
// r2's mapping needs only 96 weight VGPRs but its small LDS let the
// heuristic target 2 blocks/CU -> 64-reg budget -> full spill.
//
// This round: r2 mapping + r3 LDS pad. 1024-thread blocks, LDS padded to
// ~84 KB (> 80 KB) so only 1 block/CU fits AT COMPILE TIME -> max 16
// waves/CU = 4 waves/EU -> the 128-VGPR budget is structural AND sufficient:
//   thread t: gate row g = t>>1 (PyTorch order i,f,g,o), K-half h = t&1.
//   Stationary weights: 3 matrices x 32 half2 = 96 VGPRs.
//   Partner t^1 (same wave) holds the other K-half; one __shfl_xor(.,1)
//   combines; even lane writes layer-0 gate, odd lane layer-1 gate.
// Two-layer fused pipeline (layer 1 lags by one step), 2 barriers/step.
// fp32 accumulation via v_dot2_f32_f16; h states fp16 in LDS (wave-uniform
// broadcast reads, conflict-free); c states fp32 in registers.
// Row loop deliberately NOT unrolled (unroll 1) to cap live ranges; k-loop
// fully unrolled so weight arrays stay in registers.

#define SEQ   512
#define BATCH 1024
#define HID   128
#define ROWS  4
#define NTHR  1024
#define NBLK  (BATCH / ROWS)

typedef _Float16 half_t;
typedef __attribute__((ext_vector_type(2))) _Float16 half2_t;
typedef __attribute__((ext_vector_type(8))) _Float16 half8_t;

__device__ __forceinline__ float dot2f(half2_t a, half2_t b, float c) {
    return __builtin_amdgcn_fdot2(a, b, c, false);
}
__device__ __forceinline__ float sigm(float x) {
    return 1.0f / (1.0f + __expf(-x));
}
__device__ __forceinline__ float tanh_fast(float x) {
    float e = __expf(2.0f * x);
    return 1.0f - 2.0f / (e + 1.0f);
}

__global__ void __launch_bounds__(NTHR)
__attribute__((amdgpu_waves_per_eu(4, 4)))
lstm2_fused(const float* __restrict__ x,
            const float* __restrict__ w_ih0, const float* __restrict__ w_hh0,
            const float* __restrict__ b_ih0, const float* __restrict__ b_hh0,
            const float* __restrict__ w_ih1, const float* __restrict__ w_hh1,
            const float* __restrict__ b_ih1, const float* __restrict__ b_hh1,
            const float* __restrict__ fc_w,  const float* __restrict__ fc_b,
            float* __restrict__ out)
{
    const int t    = threadIdx.x;
    const int g    = t >> 1;            // gate row 0..511
    const int h    = t & 1;             // K-half: elements [h*64, h*64+64)
    const int row0 = blockIdx.x * ROWS;

    __shared__ __align__(16) half_t h1s[ROWS][HID];
    __shared__ __align__(16) half_t h2s[ROWS][HID];
    __shared__ float gbuf0[ROWS][4 * HID];   // layer-0 pre-activations
    __shared__ float gbuf1[ROWS][4 * HID];   // layer-1 pre-activations
    __shared__ float xs[2][ROWS][5];         // double-buffered x slices
    // Occupancy pad: total static LDS ~84 KB > 80 KB => only 1 block/CU fits
    // at compile time => max 4 waves/EU => 128-VGPR budget (which suffices).
    // First 16 floats double as the epilogue scratch (can't be DCE'd).
    __shared__ float ldspad[16384];

    // ---- stationary weights: fp32 -> fp16, 3 x 32 half2 = 96 VGPRs ----
    half2_t w0[32], w1[32], w2[32];
    {
        const float* p = w_hh0 + (size_t)g * HID + h * 64;
#pragma unroll
        for (int k = 0; k < 32; ++k) {
            float2 a = *(const float2*)(p + 2 * k);
            half2_t v; v[0] = (half_t)a.x; v[1] = (half_t)a.y; w0[k] = v;
        }
    }
    {
        const float* p = w_ih1 + (size_t)g * HID + h * 64;
#pragma unroll
        for (int k = 0; k < 32; ++k) {
            float2 a = *(const float2*)(p + 2 * k);
            half2_t v; v[0] = (half_t)a.x; v[1] = (half_t)a.y; w1[k] = v;
        }
    }
    {
        const float* p = w_hh1 + (size_t)g * HID + h * 64;
#pragma unroll
        for (int k = 0; k < 32; ++k) {
            float2 a = *(const float2*)(p + 2 * k);
            half2_t v; v[0] = (half_t)a.x; v[1] = (half_t)a.y; w2[k] = v;
        }
    }
    float wx[5];
#pragma unroll
    for (int d = 0; d < 5; ++d) wx[d] = w_ih0[g * 5 + d];
    const float bias0 = b_ih0[g] + b_hh0[g];
    const float bias1 = b_ih1[g] + b_hh1[g];

    // ---- update-phase mapping ----
    const bool lower = (t < 512);            // layer-0 update vs layer-1 update
    const int  ut = t & 511;
    const int  ur = ut >> 7;                 // batch row
    const int  uj = ut & (HID - 1);          // hidden index
    float cst = 0.0f, h2v = 0.0f;
    const float* gbp  = lower ? &gbuf0[ur][0] : &gbuf1[ur][0];
    half_t*      hdst = lower ? &h1s[ur][0]  : &h2s[ur][0];

    if (t < ROWS * HID) { h1s[ur][uj] = (half_t)0.0f; h2s[ur][uj] = (half_t)0.0f; }
    if (t < ROWS * 5)
        xs[0][t / 5][t % 5] = x[(size_t)(row0 + t / 5) * (SEQ * 5) + (t % 5)];
    __syncthreads();

    for (int s = 0; s <= SEQ; ++s) {
        const int pb = s & 1;
        // ---- gate phase: layer-0 gates(s) + layer-1 gates(s-1) ----
#pragma unroll 1
        for (int r = 0; r < ROWS; ++r) {
            float xb = bias0;
#pragma unroll
            for (int d = 0; d < 5; ++d) xb = fmaf(wx[d], xs[pb][r][d], xb);
            float a0 = h ? 0.0f : xb;
            float a1 = h ? 0.0f : bias1;
            const half8_t* hp1 = (const half8_t*)(&h1s[r][h * 64]);
            const half8_t* hp2 = (const half8_t*)(&h2s[r][h * 64]);
#pragma unroll
            for (int k = 0; k < 8; ++k) {
                half8_t v = hp1[k];    // 2 unique addrs/wave -> free broadcast
                half2_t v0 = __builtin_shufflevector(v, v, 0, 1);
                half2_t v1 = __builtin_shufflevector(v, v, 2, 3);
                half2_t v2 = __builtin_shufflevector(v, v, 4, 5);
                half2_t v3 = __builtin_shufflevector(v, v, 6, 7);
                a0 = dot2f(v0, w0[4 * k + 0], a0);  a1 = dot2f(v0, w1[4 * k + 0], a1);
                a0 = dot2f(v1, w0[4 * k + 1], a0);  a1 = dot2f(v1, w1[4 * k + 1], a1);
                a0 = dot2f(v2, w0[4 * k + 2], a0);  a1 = dot2f(v2, w1[4 * k + 2], a1);
                a0 = dot2f(v3, w0[4 * k + 3], a0);  a1 = dot2f(v3, w1[4 * k + 3], a1);
            }
#pragma unroll
            for (int k = 0; k < 8; ++k) {
                half8_t v = hp2[k];
                a1 = dot2f(__builtin_shufflevector(v, v, 0, 1), w2[4 * k + 0], a1);
                a1 = dot2f(__builtin_shufflevector(v, v, 2, 3), w2[4 * k + 1], a1);
                a1 = dot2f(__builtin_shufflevector(v, v, 4, 5), w2[4 * k + 2], a1);
                a1 = dot2f(__builtin_shufflevector(v, v, 6, 7), w2[4 * k + 3], a1);
            }
            a0 += __shfl_xor(a0, 1);
            a1 += __shfl_xor(a1, 1);
            if (h == 0) gbuf0[r][g] = a0;   // even lane: layer-0 gate
            else        gbuf1[r][g] = a1;   // odd lane: layer-1 gate
        }
        // prefetch x for next step's layer-0 phase
        if (t < ROWS * 5) {
            int xi = (s + 1 < SEQ) ? (s + 1) : (SEQ - 1);
            xs[(s + 1) & 1][t / 5][t % 5] =
                x[(size_t)(row0 + t / 5) * (SEQ * 5) + xi * 5 + (t % 5)];
        }
        __syncthreads();

        // ---- update phase: h1[s] (lower), h2[s-1] (upper, skip at s==0) ----
        if (lower | (s > 0)) {
            float gi = gbp[uj];
            float gf = gbp[HID + uj];
            float gg = gbp[2 * HID + uj];
            float go = gbp[3 * HID + uj];
            float iv = sigm(gi), fv = sigm(gf), gv = tanh_fast(gg), ov = sigm(go);
            cst = fmaf(fv, cst, iv * gv);
            float hv_ = ov * tanh_fast(cst);
            hdst[uj] = (half_t)hv_;
            h2v = hv_;                      // meaningful for upper threads only
        }
        __syncthreads();
    }

    // ---- epilogue: out[row] = fc_b + sum_j fc_w[j] * h2[511][row][j] ----
    float p = (t >= 512) ? fc_w[uj] * h2v : 0.0f;
#pragma unroll
    for (int off = 32; off > 0; off >>= 1) p += __shfl_xor(p, off);
    if ((t & 63) == 0) ldspad[t >> 6] = p;
    __syncthreads();
    if (t < ROWS) out[row0 + t] = fc_b[0] + ldspad[8 + 2 * t] + ldspad[8 + 2 * t + 1];
}

extern "C" void kernel_launch(void* const* d_in, const int* in_sizes, int n_in,
                              void* d_out, int out_size, void* d_ws, size_t ws_size,
                              hipStream_t stream) {
    (void)in_sizes; (void)n_in; (void)d_ws; (void)ws_size; (void)out_size;
    const float* x     = (const float*)d_in[0];
    const float* w_ih0 = (const float*)d_in[1];
    const float* w_hh0 = (const float*)d_in[2];
    const float* b_ih0 = (const float*)d_in[3];
    const float* b_hh0 = (const float*)d_in[4];
    const float* w_ih1 = (const float*)d_in[5];
    const float* w_hh1 = (const float*)d_in[6];
    const float* b_ih1 = (const float*)d_in[7];
    const float* b_hh1 = (const float*)d_in[8];
    const float* fc_w  = (const float*)d_in[9];
    const float* fc_b  = (const float*)d_in[10];
    float* out = (float*)d_out;

    lstm2_fused<<<NBLK, NTHR, 0, stream>>>(x, w_ih0, w_hh0, b_ih0, b_hh0,
                                           w_ih1, w_hh1, b_ih1, b_hh1,
                                           fc_w, fc_b, out);
}

// Round 6
// 2797.220 us; speedup vs baseline: 1.0133x; 1.0133x over previous
//
#include <hip/hip_runtime.h>

// 2-layer LSTM (H=128) + FC, round 6 (= round-5 design, compile fix:
// removed the bogus "no-op silencer" line).
//
// r1-r4 lesson: the allocator grants 128 VGPRs to 512-thread blocks and 64
// to 1024-thread blocks, period. Any design storing all 384 KB (fp16) of
// the three big weight matrices in registers spills to scratch (50-130 MB
// of HBM churn per launch). Fix is structural: layer 1 never feeds back
// into layer 0, so run the two layers as sequential per-block phases:
//   Phase 1: layer-0 recurrence. w_hh0 row per thread = 64 VGPRs. h1[s]
//            stored fp16 to d_ws (128 MB).
//   Phase 2: layer-1 recurrence. w_hh1 row per thread = 64 VGPRs; w_ih1
//            in LDS (128 KB, transposed [c][q][gate][4] layout -> b64
//            reads, lane stride 8 B, conflict-free); h1[s] streamed from
//            d_ws with 1-step prefetch (2 B/thread/step, latency hidden).
// Per-phase register need ~110 < 128 grant => no spill by construction.
// 512 threads (8 waves), grid 256 = 1 block/CU (139 KB LDS forces it).
// fp32 accumulation via v_dot2_f32_f16; h states fp16 (validated r1-r4,
// absmax 1.2e-4 vs 5.1e-4 threshold); c states fp32 in registers.

#define SEQ   512
#define HID   128
#define ROWS  4
#define NTHR  512
#define NBLK  256

typedef _Float16 half_t;
typedef __attribute__((ext_vector_type(2))) _Float16 half2_t;
typedef __attribute__((ext_vector_type(4))) _Float16 half4_t;
typedef __attribute__((ext_vector_type(8))) _Float16 half8_t;

__device__ __forceinline__ float dot2f(half2_t a, half2_t b, float c) {
    return __builtin_amdgcn_fdot2(a, b, c, false);
}
__device__ __forceinline__ float sigm(float x) {
    return 1.0f / (1.0f + __expf(-x));
}
__device__ __forceinline__ float tanh_fast(float x) {
    float e = __expf(2.0f * x);
    return 1.0f - 2.0f / (e + 1.0f);
}

__global__ void __launch_bounds__(NTHR)
lstm2_phased(const float* __restrict__ x,
             const float* __restrict__ w_ih0, const float* __restrict__ w_hh0,
             const float* __restrict__ b_ih0, const float* __restrict__ b_hh0,
             const float* __restrict__ w_ih1, const float* __restrict__ w_hh1,
             const float* __restrict__ b_ih1, const float* __restrict__ b_hh1,
             const float* __restrict__ fc_w,  const float* __restrict__ fc_b,
             half_t* __restrict__ h1g,        // d_ws: [NBLK][SEQ][ROWS*HID] fp16
             float* __restrict__ out)
{
    const int t    = threadIdx.x;        // gate row 0..511 in gate phases
    const int ur   = t >> 7;             // update mapping: batch row
    const int uj   = t & (HID - 1);      // update mapping: hidden index
    const int row0 = blockIdx.x * ROWS;

    // w_ih1 transposed: [chunk c: k in 32c..32c+32)][q: k=32c+4q..+4][gate][4 f16]
    __shared__ half4_t w1T[4][8][512];                    // 128 KB
    __shared__ __align__(16) half_t hs[ROWS][HID];        // h1 (ph1) / h2 (ph2)
    __shared__ __align__(16) half_t stg[2][ROWS][HID];    // ph2 h1 staging
    __shared__ float gbuf[ROWS][4 * HID];                 // pre-activations
    __shared__ float xs[2][ROWS][8];                      // x slices (dbuf)
    __shared__ float wpart[8];                            // epilogue partials

    const size_t hbase = (size_t)blockIdx.x * SEQ * (ROWS * HID);

    // ================= PHASE 1: layer 0 =================
    half2_t wA[64];                      // one 128-wide weight row, fp16
#pragma unroll
    for (int k = 0; k < 64; ++k) {
        float2 a = *(const float2*)(w_hh0 + (size_t)t * HID + 2 * k);
        half2_t v; v[0] = (half_t)a.x; v[1] = (half_t)a.y; wA[k] = v;
    }
    float wx[5];
#pragma unroll
    for (int d = 0; d < 5; ++d) wx[d] = w_ih0[t * 5 + d];
    float bias = b_ih0[t] + b_hh0[t];

    float cst = 0.0f;
    hs[ur][uj] = (half_t)0.0f;
    if (t < ROWS * 5)
        xs[0][t / 5][t % 5] = x[(size_t)(row0 + t / 5) * (SEQ * 5) + (t % 5)];
    __syncthreads();

    for (int s = 0; s < SEQ; ++s) {
        const int pb = s & 1;
        float acc[ROWS];
#pragma unroll
        for (int r = 0; r < ROWS; ++r) {
            float a = bias;
#pragma unroll
            for (int d = 0; d < 5; ++d) a = fmaf(wx[d], xs[pb][r][d], a);
            acc[r] = a;
        }
#pragma unroll
        for (int r = 0; r < ROWS; ++r) {
            const half8_t* hp = (const half8_t*)(&hs[r][0]);
#pragma unroll
            for (int k = 0; k < 16; ++k) {
                half8_t v = hp[k];          // wave-uniform broadcast b128
                acc[r] = dot2f(__builtin_shufflevector(v, v, 0, 1), wA[4 * k + 0], acc[r]);
                acc[r] = dot2f(__builtin_shufflevector(v, v, 2, 3), wA[4 * k + 1], acc[r]);
                acc[r] = dot2f(__builtin_shufflevector(v, v, 4, 5), wA[4 * k + 2], acc[r]);
                acc[r] = dot2f(__builtin_shufflevector(v, v, 6, 7), wA[4 * k + 3], acc[r]);
            }
        }
#pragma unroll
        for (int r = 0; r < ROWS; ++r) gbuf[r][t] = acc[r];
        if (t < ROWS * 5) {
            int xi = (s + 1 < SEQ) ? (s + 1) : (SEQ - 1);
            xs[(s + 1) & 1][t / 5][t % 5] =
                x[(size_t)(row0 + t / 5) * (SEQ * 5) + xi * 5 + (t % 5)];
        }
        __syncthreads();
        {   // pointwise update of h1 element (ur, uj)
            float gi = gbuf[ur][uj];
            float gf = gbuf[ur][HID + uj];
            float gg = gbuf[ur][2 * HID + uj];
            float go = gbuf[ur][3 * HID + uj];
            float iv = sigm(gi), fv = sigm(gf), gv = tanh_fast(gg), ov = sigm(go);
            cst = fmaf(fv, cst, iv * gv);
            half_t hv = (half_t)(ov * tanh_fast(cst));
            hs[ur][uj] = hv;
            h1g[hbase + (size_t)s * (ROWS * HID) + t] = hv;   // contiguous 1 KB
        }
        __syncthreads();
    }

    // ================= PHASE 2: layer 1 =================
    // reload stationary row: w_hh1 (reuses wA registers; disjoint live range)
#pragma unroll
    for (int k = 0; k < 64; ++k) {
        float2 a = *(const float2*)(w_hh1 + (size_t)t * HID + 2 * k);
        half2_t v; v[0] = (half_t)a.x; v[1] = (half_t)a.y; wA[k] = v;
    }
    bias = b_ih1[t] + b_hh1[t];
    // cooperative transpose-load of w_ih1 into LDS (one-time, 256 KB read)
    {
        const float* p = w_ih1 + (size_t)t * HID;
#pragma unroll
        for (int c = 0; c < 4; ++c)
#pragma unroll
            for (int q = 0; q < 8; ++q) {
                float4 a = *(const float4*)(p + c * 32 + q * 4);
                half4_t v; v[0] = (half_t)a.x; v[1] = (half_t)a.y;
                v[2] = (half_t)a.z; v[3] = (half_t)a.w;
                w1T[c][q][t] = v;
            }
    }
    hs[ur][uj] = (half_t)0.0f;
    cst = 0.0f;
    float h2v = 0.0f;
    ((half_t*)stg)[t] = h1g[hbase + t];   // preload stage[0] = h1[0]
    __syncthreads();

    for (int s = 0; s < SEQ; ++s) {
        const int cur = s & 1;
        // prefetch h1[s+1] (consumed next step; ~2500 cyc of slack)
        half_t pv = (half_t)0.0f;
        if (s + 1 < SEQ) pv = h1g[hbase + (size_t)(s + 1) * (ROWS * HID) + t];

        float acc[ROWS];
#pragma unroll
        for (int r = 0; r < ROWS; ++r) acc[r] = bias;
        // w_hh1 . h2[s-1]   (registers x LDS broadcast)
#pragma unroll
        for (int r = 0; r < ROWS; ++r) {
            const half8_t* hp = (const half8_t*)(&hs[r][0]);
#pragma unroll
            for (int k = 0; k < 16; ++k) {
                half8_t v = hp[k];
                acc[r] = dot2f(__builtin_shufflevector(v, v, 0, 1), wA[4 * k + 0], acc[r]);
                acc[r] = dot2f(__builtin_shufflevector(v, v, 2, 3), wA[4 * k + 1], acc[r]);
                acc[r] = dot2f(__builtin_shufflevector(v, v, 4, 5), wA[4 * k + 2], acc[r]);
                acc[r] = dot2f(__builtin_shufflevector(v, v, 6, 7), wA[4 * k + 3], acc[r]);
            }
        }
        // w_ih1 . h1[s]     (LDS weights, chunked through 16 temp half2)
#pragma unroll
        for (int c = 0; c < 4; ++c) {
            half2_t wt[16];
#pragma unroll
            for (int q = 0; q < 8; ++q) {
                half4_t w4 = w1T[c][q][t];          // b64, stride 8 B: conflict-free
                wt[2 * q]     = __builtin_shufflevector(w4, w4, 0, 1);
                wt[2 * q + 1] = __builtin_shufflevector(w4, w4, 2, 3);
            }
#pragma unroll
            for (int r = 0; r < ROWS; ++r) {
                const half8_t* sp = (const half8_t*)(&stg[cur][r][c * 32]);
#pragma unroll
                for (int o = 0; o < 4; ++o) {
                    half8_t v = sp[o];
                    acc[r] = dot2f(__builtin_shufflevector(v, v, 0, 1), wt[4 * o + 0], acc[r]);
                    acc[r] = dot2f(__builtin_shufflevector(v, v, 2, 3), wt[4 * o + 1], acc[r]);
                    acc[r] = dot2f(__builtin_shufflevector(v, v, 4, 5), wt[4 * o + 2], acc[r]);
                    acc[r] = dot2f(__builtin_shufflevector(v, v, 6, 7), wt[4 * o + 3], acc[r]);
                }
            }
        }
#pragma unroll
        for (int r = 0; r < ROWS; ++r) gbuf[r][t] = acc[r];
        __syncthreads();
        {   // pointwise update of h2 element (ur, uj)
            float gi = gbuf[ur][uj];
            float gf = gbuf[ur][HID + uj];
            float gg = gbuf[ur][2 * HID + uj];
            float go = gbuf[ur][3 * HID + uj];
            float iv = sigm(gi), fv = sigm(gf), gv = tanh_fast(gg), ov = sigm(go);
            cst = fmaf(fv, cst, iv * gv);
            h2v = ov * tanh_fast(cst);
            hs[ur][uj] = (half_t)h2v;
            ((half_t*)stg)[(1 - cur) * (ROWS * HID) + t] = pv;  // stage h1[s+1]
        }
        __syncthreads();
    }

    // ---- epilogue: out[row] = fc_b + sum_j fc_w[j] * h2[511][row][j] ----
    float p = fc_w[uj] * h2v;
#pragma unroll
    for (int off = 32; off > 0; off >>= 1) p += __shfl_xor(p, off);
    if ((t & 63) == 0) wpart[t >> 6] = p;
    __syncthreads();
    if (t < ROWS) out[row0 + t] = fc_b[0] + wpart[2 * t] + wpart[2 * t + 1];
}

extern "C" void kernel_launch(void* const* d_in, const int* in_sizes, int n_in,
                              void* d_out, int out_size, void* d_ws, size_t ws_size,
                              hipStream_t stream) {
    (void)in_sizes; (void)n_in; (void)ws_size; (void)out_size;
    const float* x     = (const float*)d_in[0];
    const float* w_ih0 = (const float*)d_in[1];
    const float* w_hh0 = (const float*)d_in[2];
    const float* b_ih0 = (const float*)d_in[3];
    const float* b_hh0 = (const float*)d_in[4];
    const float* w_ih1 = (const float*)d_in[5];
    const float* w_hh1 = (const float*)d_in[6];
    const float* b_ih1 = (const float*)d_in[7];
    const float* b_hh1 = (const float*)d_in[8];
    const float* fc_w  = (const float*)d_in[9];
    const float* fc_b  = (const float*)d_in[10];
    float* out = (float*)d_out;
    half_t* h1g = (half_t*)d_ws;   // needs 256*512*512*2 = 128 MB

    lstm2_phased<<<NBLK, NTHR, 0, stream>>>(x, w_ih0, w_hh0, b_ih0, b_hh0,
                                            w_ih1, w_hh1, b_ih1, b_hh1,
                                            fc_w, fc_b, h1g, out);
}

// Round 7
// 1371.044 us; speedup vs baseline: 2.0674x; 2.0402x over previous
//
#include <hip/hip_runtime.h>

// 2-layer LSTM (H=128) + FC, round 7: MFMA restructure.
//
// r6 post-mortem: the dot2 broadcast structure is DS-pipe bound (each
// broadcast ds_read_b128 delivers 16 useful B/wave but costs a full DS
// slot; 64-160 DS instr/thread-step ~= 7.2M cyc = the measured 2.8 ms).
// MFMA 16x16x32_f16 ingests a 16x32 A-tile per instruction: h-operand DS
// traffic drops 16x and the 256-dot2 VALU floor becomes 16 MFMA on the
// separate matrix pipe.
//
// Batch rows 4 -> padded to M=16 (pad waste is free; MFMA far from limit).
// Register wall (128 VGPR grant): exactly ONE stationary 64-VGPR B-frag
// set at a time; MFMA accumulators live on the unified AGPR side.
//   Phase A: layer-0 recurrence (whh0 frags stationary). x*w_ih0 (K=5)
//            done as 20 fma in pointwise threads. h1 -> d_ws (128 MB).
//   Phase B/C in 8-step chunks: B computes xg1 = bias1 + wih1*h1 (frags
//            reloaded per chunk; A-frags from gmem h1, masked to 4 real
//            rows), stores C-frag-packed fp32 to LDS (wave-private, no
//            barriers); C runs whh1 recurrence with acc init from xg1.
// Layouts (HW-verified per guide): A[m=lane&15][k=(lane>>4)*8+j];
// C/D: col=lane&15, row=(lane>>4)*4+reg. fp32 accumulation throughout;
// h states fp16 (absmax 1.2e-4 validated r1-r6); c states fp32 regs.

#define SEQ    512
#define HID    128
#define NTHR   512
#define NBLK   256
#define CHUNK  8
#define NCHUNK (SEQ / CHUNK)

typedef _Float16 half_t;
typedef __attribute__((ext_vector_type(8))) _Float16 half8_t;
typedef __attribute__((ext_vector_type(4))) float floatx4;

__device__ __forceinline__ float sigm(float v) { return 1.0f / (1.0f + __expf(-v)); }
__device__ __forceinline__ float tanh_fast(float v) {
    float e = __expf(2.0f * v);
    return 1.0f - 2.0f / (e + 1.0f);
}

__global__ void __launch_bounds__(NTHR)
lstm2_mfma(const float* __restrict__ x,
           const float* __restrict__ w_ih0, const float* __restrict__ w_hh0,
           const float* __restrict__ b_ih0, const float* __restrict__ b_hh0,
           const float* __restrict__ w_ih1, const float* __restrict__ w_hh1,
           const float* __restrict__ b_ih1, const float* __restrict__ b_hh1,
           const float* __restrict__ fc_w,  const float* __restrict__ fc_b,
           half_t* __restrict__ h1g, float* __restrict__ out)
{
    const int t   = threadIdx.x;
    const int w   = t >> 6;            // wave id: owns gate chunk [w*64, w*64+64)
    const int l   = t & 63;
    const int m16 = l & 15;            // MFMA frag row/col index
    const int kg  = l >> 4;            // MFMA frag k-group (0..3)
    const int n0  = w * 64;
    const int pr  = t & 3;             // pointwise: batch row
    const int pj  = t >> 2;            // pointwise: hidden index
    const int row0 = blockIdx.x * 4;

    // xg1 staging, C-frag packed, only the 16 real-row lanes store: 64 KB
    __shared__ __align__(16) floatx4 xgbuf[CHUNK][8][4][16];
    __shared__ __align__(16) float   gbuf[4 * HID][4];   // [gate][row], 8 KB
    __shared__ __align__(16) half_t  hbuf[16][136];      // padded h tile
    __shared__ float xs[2][4][5];
    __shared__ float ldspad[2048];     // pad LDS > 80 KB: 1 block/CU structural
    float (*wpart)[4] = (float(*)[4])ldspad;

    const size_t hb = (size_t)blockIdx.x * SEQ * 512;

    // ---- stationary B-fragments (one matrix at a time): 16 frags = 64 VGPRs
    half8_t bf[4][4];                  // [k-tile][n-tile]
    auto load_frags = [&](const float* W) {
#pragma unroll
        for (int kt = 0; kt < 4; ++kt)
#pragma unroll
            for (int nt = 0; nt < 4; ++nt) {
                const float* p = W + (size_t)(n0 + nt * 16 + m16) * HID + kt * 32 + kg * 8;
                float4 a = *(const float4*)p;
                float4 b = *(const float4*)(p + 4);
                half8_t v;
                v[0] = (half_t)a.x; v[1] = (half_t)a.y; v[2] = (half_t)a.z; v[3] = (half_t)a.w;
                v[4] = (half_t)b.x; v[5] = (half_t)b.y; v[6] = (half_t)b.z; v[7] = (half_t)b.w;
                bf[kt][nt] = v;
            }
    };

    float bias0v[4], bias1v[4];
#pragma unroll
    for (int nt = 0; nt < 4; ++nt) {
        int g = n0 + nt * 16 + m16;
        bias0v[nt] = b_ih0[g] + b_hh0[g];
        bias1v[nt] = b_ih1[g] + b_hh1[g];
    }
    // pointwise statics: w_ih0 rows for this thread's 4 gates
    float wxp[4][5];
#pragma unroll
    for (int q = 0; q < 4; ++q)
#pragma unroll
        for (int d = 0; d < 5; ++d) wxp[q][d] = w_ih0[(q * HID + pj) * 5 + d];

    // ================= PHASE A: layer 0 =================
    load_frags(w_hh0);
    for (int i = t; i < 16 * 136; i += NTHR) ((half_t*)hbuf)[i] = (half_t)0;
    if (t < 20) xs[0][t / 5][t % 5] = x[(size_t)(row0 + t / 5) * (SEQ * 5) + (t % 5)];
    __syncthreads();

    float xg0[4];
#pragma unroll
    for (int q = 0; q < 4; ++q)
        xg0[q] = fmaf(wxp[q][0], xs[0][pr][0], fmaf(wxp[q][1], xs[0][pr][1],
                 fmaf(wxp[q][2], xs[0][pr][2], fmaf(wxp[q][3], xs[0][pr][3],
                      wxp[q][4] * xs[0][pr][4]))));
    float c1 = 0.0f;

    for (int s = 0; s < SEQ; ++s) {
        half8_t af[4];
#pragma unroll
        for (int kt = 0; kt < 4; ++kt)
            af[kt] = *(const half8_t*)&hbuf[m16][kt * 32 + kg * 8];
        floatx4 acc[4];
#pragma unroll
        for (int nt = 0; nt < 4; ++nt)
            acc[nt] = (floatx4){bias0v[nt], bias0v[nt], bias0v[nt], bias0v[nt]};
#pragma unroll
        for (int kt = 0; kt < 4; ++kt)
#pragma unroll
            for (int nt = 0; nt < 4; ++nt)
                acc[nt] = __builtin_amdgcn_mfma_f32_16x16x32_f16(af[kt], bf[kt][nt], acc[nt], 0, 0, 0);
        if (l < 16) {
#pragma unroll
            for (int nt = 0; nt < 4; ++nt)
                *(floatx4*)&gbuf[n0 + nt * 16 + l][0] = acc[nt];   // rows 0..3 = regs
        }
        if (t < 20) {
            int xi = (s + 1 < SEQ) ? (s + 1) : (SEQ - 1);
            xs[(s + 1) & 1][t / 5][t % 5] = x[(size_t)(row0 + t / 5) * (SEQ * 5) + xi * 5 + (t % 5)];
        }
        __syncthreads();
        {   // pointwise: thread (pr, pj)
            float gi = gbuf[pj][pr]            + xg0[0];
            float gf = gbuf[HID + pj][pr]      + xg0[1];
            float gg = gbuf[2 * HID + pj][pr]  + xg0[2];
            float go = gbuf[3 * HID + pj][pr]  + xg0[3];
            float iv = sigm(gi), fv = sigm(gf), gv = tanh_fast(gg), ov = sigm(go);
            c1 = fmaf(fv, c1, iv * gv);
            half_t hv = (half_t)(ov * tanh_fast(c1));
            hbuf[pr][pj] = hv;
            h1g[hb + (size_t)s * 512 + pr * HID + pj] = hv;
            const float* xr = xs[(s + 1) & 1][pr];
#pragma unroll
            for (int q = 0; q < 4; ++q)
                xg0[q] = fmaf(wxp[q][0], xr[0], fmaf(wxp[q][1], xr[1],
                         fmaf(wxp[q][2], xr[2], fmaf(wxp[q][3], xr[3], wxp[q][4] * xr[4]))));
        }
        __syncthreads();
    }

    // ================= PHASE B/C: layer 1, chunked =================
    __threadfence();
    __syncthreads();
    for (int i = t; i < 16 * 136; i += NTHR) ((half_t*)hbuf)[i] = (half_t)0;
    __syncthreads();

    float c2 = 0.0f, h2v = 0.0f;
    const half8_t zero8 = {0, 0, 0, 0, 0, 0, 0, 0};

    for (int ch = 0; ch < NCHUNK; ++ch) {
        const int sb = ch * CHUNK;
        // ---- B: xg1[s] = bias1 + wih1 . h1[s], fragment-packed into LDS ----
        load_frags(w_ih1);
#pragma unroll 1
        for (int q = 0; q < CHUNK; ++q) {
            const int s = sb + q;
            half8_t af[4];
#pragma unroll
            for (int kt = 0; kt < 4; ++kt) {
                half8_t v = zero8;
                if (m16 < 4)
                    v = *(const half8_t*)(h1g + hb + (size_t)s * 512 + m16 * HID + kt * 32 + kg * 8);
                af[kt] = v;
            }
            floatx4 acc[4];
#pragma unroll
            for (int nt = 0; nt < 4; ++nt)
                acc[nt] = (floatx4){bias1v[nt], bias1v[nt], bias1v[nt], bias1v[nt]};
#pragma unroll
            for (int kt = 0; kt < 4; ++kt)
#pragma unroll
                for (int nt = 0; nt < 4; ++nt)
                    acc[nt] = __builtin_amdgcn_mfma_f32_16x16x32_f16(af[kt], bf[kt][nt], acc[nt], 0, 0, 0);
            if (l < 16) {
#pragma unroll
                for (int nt = 0; nt < 4; ++nt) xgbuf[q][w][nt][l] = acc[nt];
            }
        }
        // ---- C: recurrence gates = xg1[s] + whh1 . h2[s-1] ----
        load_frags(w_hh1);
#pragma unroll 1
        for (int q = 0; q < CHUNK; ++q) {
            half8_t af[4];
#pragma unroll
            for (int kt = 0; kt < 4; ++kt)
                af[kt] = *(const half8_t*)&hbuf[m16][kt * 32 + kg * 8];
            floatx4 acc[4];
#pragma unroll
            for (int nt = 0; nt < 4; ++nt)
                acc[nt] = (l < 16) ? xgbuf[q][w][nt][l] : (floatx4){0.f, 0.f, 0.f, 0.f};
#pragma unroll
            for (int kt = 0; kt < 4; ++kt)
#pragma unroll
                for (int nt = 0; nt < 4; ++nt)
                    acc[nt] = __builtin_amdgcn_mfma_f32_16x16x32_f16(af[kt], bf[kt][nt], acc[nt], 0, 0, 0);
            if (l < 16) {
#pragma unroll
                for (int nt = 0; nt < 4; ++nt)
                    *(floatx4*)&gbuf[n0 + nt * 16 + l][0] = acc[nt];
            }
            __syncthreads();
            {
                float gi = gbuf[pj][pr];
                float gf = gbuf[HID + pj][pr];
                float gg = gbuf[2 * HID + pj][pr];
                float go = gbuf[3 * HID + pj][pr];
                float iv = sigm(gi), fv = sigm(gf), gv = tanh_fast(gg), ov = sigm(go);
                c2 = fmaf(fv, c2, iv * gv);
                h2v = ov * tanh_fast(c2);
                hbuf[pr][pj] = (half_t)h2v;
            }
            __syncthreads();
        }
    }

    // ---- epilogue: out[row] = fc_b + sum_j fc_w[j] * h2[511][row][j] ----
    float p = fc_w[pj] * h2v;
    p += __shfl_xor(p, 4);
    p += __shfl_xor(p, 8);
    p += __shfl_xor(p, 16);
    p += __shfl_xor(p, 32);
    if (l < 4) wpart[w][l] = p;       // lane bits 0-1 == pr preserved
    __syncthreads();
    if (t < 4) {
        float ssum = fc_b[0];
#pragma unroll
        for (int wv = 0; wv < 8; ++wv) ssum += wpart[wv][t];
        out[row0 + t] = ssum;
    }
}

extern "C" void kernel_launch(void* const* d_in, const int* in_sizes, int n_in,
                              void* d_out, int out_size, void* d_ws, size_t ws_size,
                              hipStream_t stream) {
    (void)in_sizes; (void)n_in; (void)ws_size; (void)out_size;
    const float* x     = (const float*)d_in[0];
    const float* w_ih0 = (const float*)d_in[1];
    const float* w_hh0 = (const float*)d_in[2];
    const float* b_ih0 = (const float*)d_in[3];
    const float* b_hh0 = (const float*)d_in[4];
    const float* w_ih1 = (const float*)d_in[5];
    const float* w_hh1 = (const float*)d_in[6];
    const float* b_ih1 = (const float*)d_in[7];
    const float* b_hh1 = (const float*)d_in[8];
    const float* fc_w  = (const float*)d_in[9];
    const float* fc_b  = (const float*)d_in[10];
    float* out = (float*)d_out;
    half_t* h1g = (half_t*)d_ws;   // 256 * 512 * 512 * 2 B = 128 MB (r6-validated)

    lstm2_mfma<<<NBLK, NTHR, 0, stream>>>(x, w_ih0, w_hh0, b_ih0, b_hh0,
                                          w_ih1, w_hh1, b_ih1, b_hh1,
                                          fc_w, fc_b, h1g, out);
}

// Round 9
// 1294.750 us; speedup vs baseline: 2.1892x; 1.0589x over previous
//
#include <hip/hip_runtime.h>

// 2-layer LSTM (H=128) + FC, round 9 (= round-8 design; compile fix:
// bit_cast wrapper around cvt_pkrtz's __fp16-vector return type).
//
// r7 post-mortem: MFMA pipe busy only 24%; the loss is 2 barriers/step +
// a gbuf LDS round-trip to redistribute MFMA output to pointwise threads,
// plus per-chunk frag reloads. This round re-maps the tile so pointwise
// needs NO redistribution:
//  - N-permutation: wave w owns hidden j in [16w,16w+16); its 4 nt-frags
//    are the 4 GATE TYPES (i,f,g,o) for those j (gate row = nt*128+j).
//  - M-replication: A-tile row m = batch row m&3 (4 copies). Every lane's
//    acc reg q = batch row q, so all 64 lanes run pointwise (1 element
//    each: row kg, col j) with one dynamic reg-select; c-state 1 reg/lane.
//  => 1 barrier/step (double-buffered h tile), no gbuf, transcendentals
//     fully distributed.
// Phase A: layer-0 recurrence (whh0 frags, 64 VGPR); x-gate via 3 packed
//   dot2 per gate; h1 -> d_ws.  Phase B/C (CHUNK=16): B = wih1*h1 + bias1
//   into 128 KB LDS xgbuf (wave-private, barrier-free); C = whh1
//   recurrence, acc seeded from xgbuf.
// LDS ~137 KB -> 1 block/CU, 256-VGPR budget, need-based grant (~130).

#define SEQ    512
#define HID    128
#define NTHR   512
#define NBLK   256
#define CHUNK  16
#define NCHUNK (SEQ / CHUNK)

typedef _Float16 half_t;
typedef __attribute__((ext_vector_type(2))) _Float16 half2_t;
typedef __attribute__((ext_vector_type(8))) _Float16 half8_t;
typedef __attribute__((ext_vector_type(4))) float floatx4;

__device__ __forceinline__ half2_t pkrtz(float a, float b) {
    return __builtin_bit_cast(half2_t, __builtin_amdgcn_cvt_pkrtz(a, b));
}
__device__ __forceinline__ float dot2f(half2_t a, half2_t b, float c) {
    return __builtin_amdgcn_fdot2(a, b, c, false);
}
__device__ __forceinline__ float sigm(float v) { return 1.0f / (1.0f + __expf(-v)); }
__device__ __forceinline__ float tanh_fast(float v) {
    float e = __expf(2.0f * v);
    return 1.0f - 2.0f / (e + 1.0f);
}
// dynamic component select: v[r], r in 0..3
__device__ __forceinline__ float selr(floatx4 v, int r) {
    float a = (r & 1) ? v[1] : v[0];
    float b = (r & 1) ? v[3] : v[2];
    return (r & 2) ? b : a;
}

__global__ void __launch_bounds__(NTHR)
lstm2_mfma2(const float* __restrict__ x,
            const float* __restrict__ w_ih0, const float* __restrict__ w_hh0,
            const float* __restrict__ b_ih0, const float* __restrict__ b_hh0,
            const float* __restrict__ w_ih1, const float* __restrict__ w_hh1,
            const float* __restrict__ b_ih1, const float* __restrict__ b_hh1,
            const float* __restrict__ fc_w,  const float* __restrict__ fc_b,
            half_t* __restrict__ h1g, float* __restrict__ out)
{
    const int t   = threadIdx.x;
    const int w   = t >> 6;
    const int l   = t & 63;
    const int m16 = l & 15;            // frag row (A) / col (B,D)
    const int kg  = l >> 4;            // frag k-group; also pointwise row
    const int jj  = (w << 4) | m16;    // global hidden index 0..127
    const int rr  = m16 & 3;           // replicated batch row for A-frag row
    const int row0 = blockIdx.x * 4;

    __shared__ floatx4 xgbuf[CHUNK][8][4][16];        // 128 KB, wave-private
    __shared__ __align__(16) half_t hb[2][16][136];   // dbuf replicated h tile
    __shared__ float xs[2][4][8];                     // x slices (padded rows)
    __shared__ float wpart[8][4];

    const size_t hbase = (size_t)blockIdx.x * (SEQ * 512);

    half8_t bf[4][4];                  // stationary B-frags: 64 VGPRs
    auto load_frags = [&](const float* W) {
#pragma unroll
        for (int kt = 0; kt < 4; ++kt)
#pragma unroll
            for (int nt = 0; nt < 4; ++nt) {
                const float* p = W + (size_t)(nt * HID + jj) * HID + kt * 32 + kg * 8;
                float4 a = *(const float4*)p;
                float4 b = *(const float4*)(p + 4);
                half8_t v;
                v[0] = (half_t)a.x; v[1] = (half_t)a.y; v[2] = (half_t)a.z; v[3] = (half_t)a.w;
                v[4] = (half_t)b.x; v[5] = (half_t)b.y; v[6] = (half_t)b.z; v[7] = (half_t)b.w;
                bf[kt][nt] = v;
            }
    };

    float bias0v[4], bias1v[4];
#pragma unroll
    for (int nt = 0; nt < 4; ++nt) {
        int g = nt * HID + jj;
        bias0v[nt] = b_ih0[g] + b_hh0[g];
        bias1v[nt] = b_ih1[g] + b_hh1[g];
    }
    // layer-0 x weights, packed fp16: 3 half2 per gate type = 12 VGPRs
    half2_t wxh[4][3];
#pragma unroll
    for (int nt = 0; nt < 4; ++nt) {
        const float* p = w_ih0 + (nt * HID + jj) * 5;
        wxh[nt][0] = pkrtz(p[0], p[1]);
        wxh[nt][1] = pkrtz(p[2], p[3]);
        wxh[nt][2] = pkrtz(p[4], 0.0f);
    }

    for (int i = t; i < 2 * 16 * 136; i += NTHR) ((half_t*)hb)[i] = (half_t)0;
    if (t < 20) xs[0][t / 5][t % 5] = x[(size_t)(row0 + t / 5) * (SEQ * 5) + (t % 5)];
    load_frags(w_hh0);
    float c1 = 0.0f;
    __syncthreads();

    // ================= PHASE A: layer 0 (1 barrier/step) =================
    for (int s = 0; s < SEQ; ++s) {
        const int pb = s & 1, nb = (s + 1) & 1;
        half8_t af[4];
#pragma unroll
        for (int kt = 0; kt < 4; ++kt)
            af[kt] = *(const half8_t*)&hb[pb][m16][kt * 32 + kg * 8];
        floatx4 acc[4];
#pragma unroll
        for (int nt = 0; nt < 4; ++nt)
            acc[nt] = (floatx4){bias0v[nt], bias0v[nt], bias0v[nt], bias0v[nt]};
#pragma unroll
        for (int kt = 0; kt < 4; ++kt)
#pragma unroll
            for (int nt = 0; nt < 4; ++nt)
                acc[nt] = __builtin_amdgcn_mfma_f32_16x16x32_f16(af[kt], bf[kt][nt], acc[nt], 0, 0, 0);
        if (t < 20) {
            int xi = (s + 1 < SEQ) ? (s + 1) : (SEQ - 1);
            xs[nb][t / 5][t % 5] = x[(size_t)(row0 + t / 5) * (SEQ * 5) + xi * 5 + (t % 5)];
        }
        {   // pointwise: this lane -> (row kg, hidden jj)
            const float* xr = xs[pb][kg];
            half2_t x01 = pkrtz(xr[0], xr[1]);
            half2_t x23 = pkrtz(xr[2], xr[3]);
            half2_t x4z = pkrtz(xr[4], 0.0f);
            float gi = selr(acc[0], kg) + dot2f(x4z, wxh[0][2], dot2f(x23, wxh[0][1], dot2f(x01, wxh[0][0], 0.f)));
            float gf = selr(acc[1], kg) + dot2f(x4z, wxh[1][2], dot2f(x23, wxh[1][1], dot2f(x01, wxh[1][0], 0.f)));
            float gg = selr(acc[2], kg) + dot2f(x4z, wxh[2][2], dot2f(x23, wxh[2][1], dot2f(x01, wxh[2][0], 0.f)));
            float go = selr(acc[3], kg) + dot2f(x4z, wxh[3][2], dot2f(x23, wxh[3][1], dot2f(x01, wxh[3][0], 0.f)));
            float iv = sigm(gi), fv = sigm(gf), gv = tanh_fast(gg), ov = sigm(go);
            c1 = fmaf(fv, c1, iv * gv);
            half_t hh = (half_t)(ov * tanh_fast(c1));
#pragma unroll
            for (int a2 = 0; a2 < 4; ++a2) hb[nb][kg + 4 * a2][jj] = hh;   // 4 copies
            h1g[hbase + (size_t)s * 512 + kg * HID + jj] = hh;
        }
        __syncthreads();
    }

    // ================= PHASE B/C: layer 1, CHUNK=16 =================
    __threadfence();
    __syncthreads();
    for (int i = t; i < 2 * 16 * 136; i += NTHR) ((half_t*)hb)[i] = (half_t)0;
    float c2 = 0.0f, h2v = 0.0f;
    __syncthreads();

    for (int ch = 0; ch < NCHUNK; ++ch) {
        // ---- B: xg1[s] = bias1 + wih1 . h1[s] (barrier-free, wave-private) ----
        load_frags(w_ih1);
#pragma unroll 1
        for (int q = 0; q < CHUNK; ++q) {
            const int s = ch * CHUNK + q;
            half8_t af[4];
#pragma unroll
            for (int kt = 0; kt < 4; ++kt)
                af[kt] = *(const half8_t*)(h1g + hbase + (size_t)s * 512 + rr * HID + kt * 32 + kg * 8);
            floatx4 acc[4];
#pragma unroll
            for (int nt = 0; nt < 4; ++nt)
                acc[nt] = (floatx4){bias1v[nt], bias1v[nt], bias1v[nt], bias1v[nt]};
#pragma unroll
            for (int kt = 0; kt < 4; ++kt)
#pragma unroll
                for (int nt = 0; nt < 4; ++nt)
                    acc[nt] = __builtin_amdgcn_mfma_f32_16x16x32_f16(af[kt], bf[kt][nt], acc[nt], 0, 0, 0);
            if (l < 16) {
#pragma unroll
                for (int nt = 0; nt < 4; ++nt) xgbuf[q][w][nt][m16] = acc[nt];
            }
        }
        // ---- C: recurrence (1 barrier/step) ----
        load_frags(w_hh1);
#pragma unroll 1
        for (int q = 0; q < CHUNK; ++q) {
            const int s = ch * CHUNK + q;
            const int pb = s & 1, nb = (s + 1) & 1;
            half8_t af[4];
#pragma unroll
            for (int kt = 0; kt < 4; ++kt)
                af[kt] = *(const half8_t*)&hb[pb][m16][kt * 32 + kg * 8];
            floatx4 acc[4];
#pragma unroll
            for (int nt = 0; nt < 4; ++nt)
                acc[nt] = xgbuf[q][w][nt][m16];      // 4-way broadcast b128
#pragma unroll
            for (int kt = 0; kt < 4; ++kt)
#pragma unroll
                for (int nt = 0; nt < 4; ++nt)
                    acc[nt] = __builtin_amdgcn_mfma_f32_16x16x32_f16(af[kt], bf[kt][nt], acc[nt], 0, 0, 0);
            {
                float gi = selr(acc[0], kg);
                float gf = selr(acc[1], kg);
                float gg = selr(acc[2], kg);
                float go = selr(acc[3], kg);
                float iv = sigm(gi), fv = sigm(gf), gv = tanh_fast(gg), ov = sigm(go);
                c2 = fmaf(fv, c2, iv * gv);
                h2v = ov * tanh_fast(c2);
                half_t hh = (half_t)h2v;
#pragma unroll
                for (int a2 = 0; a2 < 4; ++a2) hb[nb][kg + 4 * a2][jj] = hh;
            }
            __syncthreads();
        }
    }

    // ---- epilogue: out[row] = fc_b + sum_j fc_w[j] * h2[511][row][j] ----
    float p = fc_w[jj] * h2v;                        // lane = (row kg, col jj)
    p += __shfl_xor(p, 1);
    p += __shfl_xor(p, 2);
    p += __shfl_xor(p, 4);
    p += __shfl_xor(p, 8);
    if (m16 == 0) wpart[w][kg] = p;
    __syncthreads();
    if (t < 4) {
        float ssum = fc_b[0];
#pragma unroll
        for (int wv = 0; wv < 8; ++wv) ssum += wpart[wv][t];
        out[row0 + t] = ssum;
    }
}

extern "C" void kernel_launch(void* const* d_in, const int* in_sizes, int n_in,
                              void* d_out, int out_size, void* d_ws, size_t ws_size,
                              hipStream_t stream) {
    (void)in_sizes; (void)n_in; (void)ws_size; (void)out_size;
    const float* x     = (const float*)d_in[0];
    const float* w_ih0 = (const float*)d_in[1];
    const float* w_hh0 = (const float*)d_in[2];
    const float* b_ih0 = (const float*)d_in[3];
    const float* b_hh0 = (const float*)d_in[4];
    const float* w_ih1 = (const float*)d_in[5];
    const float* w_hh1 = (const float*)d_in[6];
    const float* b_ih1 = (const float*)d_in[7];
    const float* b_hh1 = (const float*)d_in[8];
    const float* fc_w  = (const float*)d_in[9];
    const float* fc_b  = (const float*)d_in[10];
    float* out = (float*)d_out;
    half_t* h1g = (half_t*)d_ws;   // 128 MB (validated r6/r7)

    lstm2_mfma2<<<NBLK, NTHR, 0, stream>>>(x, w_ih0, w_hh0, b_ih0, b_hh0,
                                           w_ih1, w_hh1, b_ih1, b_hh1,
                                           fc_w, fc_b, h1g, out);
}